// Round 4
// baseline (1847.667 us; speedup 1.0000x reference)
//
#include <hip/hip_runtime.h>
#include <hip/hip_bf16.h>

// UnrolledRNN on MI355X (gfx950) — two-phase, one-wave register-only recurrence.
// Phase 1 (parallel, all CUs): xh[b,t,:] = x[b,t,:] @ Wxh + bxh -> bf16 in d_ws.
// Phase 2 (serial, 16 blocks x 1 wave): h = tanh(xh_t + h @ Whh_sigma2), all in
// registers. sigma2 column permutation: acc tile T (T=0..7), slot (lg, r) holds
//   j = 32*(T&3) + 8*lg + 4*(T>>2) + r,  b = lane&15.
// Under sigma2, each lane's 32 tanh'd values ARE exactly its 4 next-step MFMA
// B-fragments (frag c = [acc[c] r0..3, acc[c+4] r0..3] packed bf16):
//   ZERO LDS, ZERO barriers, ZERO cross-lane ops in the 2048-step loop.
// Whh lives as 32 A-frags (128 VGPR); xh prefetched 4 steps deep (4x dwordx4
// per lane per step). Per-step cost = pure single-wave issue (MFMA+VALU).

#define SEQ   2048
#define HID   128
#define BATCH 256
#define BD    16

typedef __attribute__((ext_vector_type(8))) short    short8;
typedef __attribute__((ext_vector_type(4))) float    f32x4;
typedef __attribute__((ext_vector_type(4))) float    f4;
typedef __attribute__((ext_vector_type(2))) unsigned u32x2;
typedef __attribute__((ext_vector_type(4))) unsigned u32x4;

union F8 { unsigned u[4]; short8 s; };

__device__ __forceinline__ unsigned pkbf(float a, float b) {
    union { __hip_bfloat16 h[2]; unsigned u; } t;
    t.h[0] = __float2bfloat16(a);
    t.h[1] = __float2bfloat16(b);
    return t.u;
}

__device__ __forceinline__ float blo(unsigned u) {
    union { unsigned v; float f; } t; t.v = u << 16; return t.f;
}
__device__ __forceinline__ float bhi(unsigned u) {
    union { unsigned v; float f; } t; t.v = u & 0xffff0000u; return t.f;
}

__device__ __forceinline__ float tanh_fast(float x) {
    float e = __builtin_amdgcn_exp2f(x * 2.8853900817779268f);
    return 1.0f - 2.0f * __builtin_amdgcn_rcpf(e + 1.0f);
}

__device__ __forceinline__ void block_sync() {
    asm volatile("s_waitcnt lgkmcnt(0)" ::: "memory");
    __builtin_amdgcn_s_barrier();
    asm volatile("" ::: "memory");
}

#define MFMA16(A,B,C) __builtin_amdgcn_mfma_f32_16x16x32_bf16((A),(B),(C),0,0,0)

// =====================================================================
// Phase 1: xh = x @ Wxh + bxh, bf16 [BATCH*SEQ][HID] in ws (plain j order).
// =====================================================================
__launch_bounds__(256, 1)
__global__ void xh_gemm_kernel(const float* __restrict__ x,
                               const float* __restrict__ Wxh,
                               const float* __restrict__ bxh,
                               __hip_bfloat16* __restrict__ xh)
{
    const int tid  = threadIdx.x;
    const int wv   = tid >> 6;
    const int lane = tid & 63;
    const int lg   = lane >> 4;
    const int lm   = lane & 15;

    const int gw = blockIdx.x * 4 + wv;
    const int NW = gridDim.x * 4;
    const int NT = (BATCH * SEQ) / 16;

    short8 wa[8][4];
    {
        #pragma unroll
        for (int T = 0; T < 8; ++T) {
            #pragma unroll
            for (int c = 0; c < 4; ++c) {
                F8 f;
                #pragma unroll
                for (int e2 = 0; e2 < 4; ++e2) {
                    int k = 32*c + 8*lg + 2*e2;
                    f.u[e2] = pkbf(Wxh[(size_t)k*HID + 16*T + lm],
                                   Wxh[(size_t)(k+1)*HID + 16*T + lm]);
                }
                wa[T][c] = f.s;
            }
        }
    }
    float bb[8][4];
    #pragma unroll
    for (int T = 0; T < 8; ++T)
        #pragma unroll
        for (int r = 0; r < 4; ++r)
            bb[T][r] = bxh[16*T + 4*lg + r];

    for (int tile = gw; tile < NT; tile += NW) {
        const float* xp = x + (size_t)tile*16*HID + (size_t)lm*HID + 8*lg;
        f4 s[8];
        #pragma unroll
        for (int c = 0; c < 4; ++c) {
            s[2*c]   = *(const f4*)(xp + 32*c);
            s[2*c+1] = *(const f4*)(xp + 32*c + 4);
        }
        F8 xf[4];
        #pragma unroll
        for (int c = 0; c < 4; ++c) {
            xf[c].u[0] = pkbf(s[2*c][0],   s[2*c][1]);
            xf[c].u[1] = pkbf(s[2*c][2],   s[2*c][3]);
            xf[c].u[2] = pkbf(s[2*c+1][0], s[2*c+1][1]);
            xf[c].u[3] = pkbf(s[2*c+1][2], s[2*c+1][3]);
        }
        __hip_bfloat16* op = xh + (size_t)(tile*16 + lm) * HID;
        #pragma unroll
        for (int T = 0; T < 8; ++T) {
            f32x4 acc = {bb[T][0], bb[T][1], bb[T][2], bb[T][3]};
            #pragma unroll
            for (int c = 0; c < 4; ++c)
                acc = MFMA16(wa[T][c], xf[c].s, acc);
            u32x2 w;
            w[0] = pkbf(acc[0], acc[1]);
            w[1] = pkbf(acc[2], acc[3]);
            *reinterpret_cast<u32x2*>(op + 16*T + 4*lg) = w;
        }
    }
}

// =====================================================================
// Phase 2: one-wave register-only recurrence.
// =====================================================================

// One step. S = u32x4[4] slot holding xh_t (frag-ordered), POFF = reload step
// offset (4..7), TRT = runtime t.
#define REC1W_STEP(S, POFF, TRT)                                              \
    {                                                                          \
        f32x4 acc[8];                                                          \
        _Pragma("unroll")                                                      \
        for (int c = 0; c < 4; ++c) {                                          \
            acc[c][0]   = blo(S[c][0]); acc[c][1]   = bhi(S[c][0]);            \
            acc[c][2]   = blo(S[c][1]); acc[c][3]   = bhi(S[c][1]);            \
            acc[c+4][0] = blo(S[c][2]); acc[c+4][1] = bhi(S[c][2]);            \
            acc[c+4][2] = blo(S[c][3]); acc[c+4][3] = bhi(S[c][3]);            \
        }                                                                      \
        if ((TRT) + 4 < SEQ) {                                                 \
            _Pragma("unroll")                                                  \
            for (int c = 0; c < 4; ++c)                                        \
                S[c] = *(const u32x4*)(xq + (POFF)*256 + 64*c);                \
        }                                                                      \
        _Pragma("unroll")                                                      \
        for (int c = 0; c < 4; ++c) {                                          \
            _Pragma("unroll")                                                  \
            for (int T = 0; T < 8; ++T)                                        \
                acc[T] = MFMA16(whf[T][c], hb[c], acc[T]);                     \
        }                                                                      \
        _Pragma("unroll")                                                      \
        for (int c = 0; c < 4; ++c) {                                          \
            F8 nf;                                                             \
            nf.u[0] = pkbf(tanh_fast(acc[c][0]),   tanh_fast(acc[c][1]));      \
            nf.u[1] = pkbf(tanh_fast(acc[c][2]),   tanh_fast(acc[c][3]));      \
            nf.u[2] = pkbf(tanh_fast(acc[c+4][0]), tanh_fast(acc[c+4][1]));    \
            nf.u[3] = pkbf(tanh_fast(acc[c+4][2]), tanh_fast(acc[c+4][3]));    \
            hb[c] = nf.s;                                                      \
        }                                                                      \
    }

__launch_bounds__(64, 1)
__global__ void rnn_rec1w_kernel(const __hip_bfloat16* __restrict__ xh,
                                 const float* __restrict__ h0,
                                 const float* __restrict__ Whh,
                                 const float* __restrict__ Wout,
                                 const float* __restrict__ bout,
                                 float* __restrict__ out)
{
    const int lane = threadIdx.x & 63;
    const int lg   = lane >> 4;
    const int lm   = lane & 15;
    const int b0   = blockIdx.x * BD;

    // Whh A-frags under sigma2: whf[T][c] lane (lg,lm) elem e =
    //   Whh[k = 32c+8lg+e][ J_T(lm) ],  J_T(m) = 32*(T&3) + 8*(m>>2) + 4*(T>>2) + (m&3)
    short8 whf[8][4];
    {
        #pragma unroll
        for (int T = 0; T < 8; ++T) {
            const int jcol = 32*(T & 3) + 8*(lm >> 2) + 4*(T >> 2) + (lm & 3);
            #pragma unroll
            for (int c = 0; c < 4; ++c) {
                F8 f;
                #pragma unroll
                for (int e2 = 0; e2 < 4; ++e2) {
                    int k = 32*c + 8*lg + 2*e2;
                    f.u[e2] = pkbf(Whh[(size_t)k*HID + jcol],
                                   Whh[(size_t)(k+1)*HID + jcol]);
                }
                whf[T][c] = f.s;
            }
        }
    }

    // h0 -> B-frags: hb[c] lane (lg,lm) elem e = h0[b0+lm][32c+8lg+e]
    short8 hb[4];
    #pragma unroll
    for (int c = 0; c < 4; ++c) {
        const float* hp = h0 + (size_t)(b0 + lm) * HID + 32*c + 8*lg;
        f4 v0 = *(const f4*)(hp);
        f4 v1 = *(const f4*)(hp + 4);
        F8 f;
        f.u[0] = pkbf(v0[0], v0[1]); f.u[1] = pkbf(v0[2], v0[3]);
        f.u[2] = pkbf(v1[0], v1[1]); f.u[3] = pkbf(v1[2], v1[3]);
        hb[c] = f.s;
    }

    // xh stream: lane (lg,lm) reads 16B per frag c at xh[b0+lm][t][32c+8lg]
    const char* xq = (const char*)xh + (size_t)(b0 + lm) * SEQ * 256 + 16*lg;

    u32x4 SA[4], SB[4], SC[4], SD[4];
    #pragma unroll
    for (int c = 0; c < 4; ++c) {
        SA[c] = *(const u32x4*)(xq + 0*256 + 64*c);
        SB[c] = *(const u32x4*)(xq + 1*256 + 64*c);
        SC[c] = *(const u32x4*)(xq + 2*256 + 64*c);
        SD[c] = *(const u32x4*)(xq + 3*256 + 64*c);
    }

    for (int t = 0; t < SEQ; t += 4) {
        REC1W_STEP(SA, 4, t);
        REC1W_STEP(SB, 5, t + 1);
        REC1W_STEP(SC, 6, t + 2);
        REC1W_STEP(SD, 7, t + 3);
        xq += 4 * 256;
    }

    // epilogue: out = h_last @ Wout + bout; h_last is in hb[] (B-frags, k=j)
    {
        #pragma unroll
        for (int T = 0; T < 8; ++T) {
            f32x4 o = {bout[16*T + 4*lg + 0], bout[16*T + 4*lg + 1],
                       bout[16*T + 4*lg + 2], bout[16*T + 4*lg + 3]};
            #pragma unroll
            for (int c = 0; c < 4; ++c) {
                F8 f;
                #pragma unroll
                for (int e2 = 0; e2 < 4; ++e2) {
                    int k = 32*c + 8*lg + 2*e2;
                    f.u[e2] = pkbf(Wout[(size_t)k*HID + 16*T + lm],
                                   Wout[(size_t)(k+1)*HID + 16*T + lm]);
                }
                o = MFMA16(f.s, hb[c], o);
            }
            float* op = out + (size_t)(b0 + lm) * HID + 16*T + 4*lg;
            *reinterpret_cast<f4*>(op) = o;
        }
    }
}

// =====================================================================
// Fallback: verified round-1 monolithic kernel (used if ws too small).
// =====================================================================
#define RNN_STEP(SLOT, P, POFF, TRT)                                          \
    {                                                                          \
        F8 xf[4];                                                              \
        _Pragma("unroll")                                                      \
        for (int c = 0; c < 4; ++c) {                                          \
            xf[c].u[0] = pkbf(SLOT[2*c][0],   SLOT[2*c][1]);                   \
            xf[c].u[1] = pkbf(SLOT[2*c][2],   SLOT[2*c][3]);                   \
            xf[c].u[2] = pkbf(SLOT[2*c+1][0], SLOT[2*c+1][1]);                 \
            xf[c].u[3] = pkbf(SLOT[2*c+1][2], SLOT[2*c+1][3]);                 \
        }                                                                      \
        if ((TRT) + 2 < SEQ) {                                                 \
            _Pragma("unroll")                                                  \
            for (int c = 0; c < 4; ++c) {                                      \
                SLOT[2*c]   = *(const f4*)(xq + (POFF)*HID + 32*c);            \
                SLOT[2*c+1] = *(const f4*)(xq + (POFF)*HID + 32*c + 4);        \
            }                                                                  \
        }                                                                      \
        f32x4 a0 = {bx[0][0], bx[0][1], bx[0][2], bx[0][3]};                   \
        f32x4 a1 = {bx[1][0], bx[1][1], bx[1][2], bx[1][3]};                   \
        _Pragma("unroll")                                                      \
        for (int c = 0; c < 4; ++c) {                                          \
            a0 = MFMA16(wxh[0][c], xf[c].s, a0);                               \
            a1 = MFMA16(wxh[1][c], xf[c].s, a1);                               \
        }                                                                      \
        block_sync();                                                          \
        _Pragma("unroll")                                                      \
        for (int c = 0; c < 4; ++c) {                                          \
            short8 hf = *reinterpret_cast<const short8*>(lds + (P)*4096 + rd[c]); \
            a0 = MFMA16(whh[0][c], hf, a0);                                    \
            a1 = MFMA16(whh[1][c], hf, a1);                                    \
        }                                                                      \
        u32x2 w0, w1;                                                          \
        w0[0] = pkbf(tanh_fast(a0[0]), tanh_fast(a0[1]));                      \
        w0[1] = pkbf(tanh_fast(a0[2]), tanh_fast(a0[3]));                      \
        w1[0] = pkbf(tanh_fast(a1[0]), tanh_fast(a1[1]));                      \
        w1[1] = pkbf(tanh_fast(a1[2]), tanh_fast(a1[3]));                      \
        *reinterpret_cast<u32x2*>(lds + ((P)^1)*4096 + hw[0]) = w0;            \
        *reinterpret_cast<u32x2*>(lds + ((P)^1)*4096 + hw[1]) = w1;            \
    }

__launch_bounds__(256, 1)
__global__ void rnn_fused_kernel(const float* __restrict__ x,
                                 const float* __restrict__ h0,
                                 const float* __restrict__ Wxh,
                                 const float* __restrict__ bxh,
                                 const float* __restrict__ Whh,
                                 const float* __restrict__ Wout,
                                 const float* __restrict__ bout,
                                 float* __restrict__ out)
{
    __shared__ __align__(16) char lds[2 * 4096];

    const int tid  = threadIdx.x;
    const int wv   = tid >> 6;
    const int lane = tid & 63;
    const int lg   = lane >> 4;
    const int lm   = lane & 15;
    const int b0   = blockIdx.x * BD;

    short8 wxh[2][4], whh[2][4];
    {
        const int col = 32*wv + lm;
        #pragma unroll
        for (int T = 0; T < 2; ++T) {
            #pragma unroll
            for (int c = 0; c < 4; ++c) {
                F8 fx, fh;
                #pragma unroll
                for (int e2 = 0; e2 < 4; ++e2) {
                    int k = 32*c + 8*lg + 2*e2;
                    fx.u[e2] = pkbf(Wxh[(size_t)k*HID + col + 16*T],
                                    Wxh[(size_t)(k+1)*HID + col + 16*T]);
                    fh.u[e2] = pkbf(Whh[(size_t)k*HID + col + 16*T],
                                    Whh[(size_t)(k+1)*HID + col + 16*T]);
                }
                wxh[T][c] = fx.s; whh[T][c] = fh.s;
            }
        }
    }
    float bx[2][4];
    #pragma unroll
    for (int T = 0; T < 2; ++T)
        #pragma unroll
        for (int r = 0; r < 4; ++r)
            bx[T][r] = bxh[32*wv + 16*T + 4*lg + r];

    int rd[4];
    #pragma unroll
    for (int c = 0; c < 4; ++c)
        rd[c] = (lm*256 + 64*c + 16*lg) ^ ((lm & 7) << 4);
    int hw[2];
    #pragma unroll
    for (int T = 0; T < 2; ++T)
        hw[T] = (lm*256 + 2*(32*wv + 16*T + 4*lg)) ^ ((lm & 7) << 4);

    {
        int b  = tid >> 4;
        int j0 = (tid & 15) * 8;
        const float* hp = h0 + (size_t)(b0 + b) * HID + j0;
        f4 v0 = *(const f4*)(hp);
        f4 v1 = *(const f4*)(hp + 4);
        F8 f;
        f.u[0] = pkbf(v0[0], v0[1]); f.u[1] = pkbf(v0[2], v0[3]);
        f.u[2] = pkbf(v1[0], v1[1]); f.u[3] = pkbf(v1[2], v1[3]);
        int off = (b*256 + 2*j0) ^ ((b & 7) << 4);
        *reinterpret_cast<short8*>(lds + off) = f.s;
    }

    const float* xq = x + (size_t)(b0 + lm) * SEQ * HID + 8*lg;
    f4 sA[8], sB[8];
    #pragma unroll
    for (int c = 0; c < 4; ++c) {
        sA[2*c]   = *(const f4*)(xq + 32*c);
        sA[2*c+1] = *(const f4*)(xq + 32*c + 4);
        sB[2*c]   = *(const f4*)(xq + HID + 32*c);
        sB[2*c+1] = *(const f4*)(xq + HID + 32*c + 4);
    }

    for (int t = 0; t < SEQ; t += 2) {
        RNN_STEP(sA, 0, 2, t);
        RNN_STEP(sB, 1, 3, t + 1);
        xq += 2 * HID;
    }

    block_sync();
    {
        short8 wo[2][4];
        const int col = 32*wv + lm;
        #pragma unroll
        for (int T = 0; T < 2; ++T) {
            #pragma unroll
            for (int c = 0; c < 4; ++c) {
                F8 f;
                #pragma unroll
                for (int e2 = 0; e2 < 4; ++e2) {
                    int k = 32*c + 8*lg + 2*e2;
                    f.u[e2] = pkbf(Wout[(size_t)k*HID + col + 16*T],
                                   Wout[(size_t)(k+1)*HID + col + 16*T]);
                }
                wo[T][c] = f.s;
            }
        }
        f32x4 o0 = {bout[32*wv + 4*lg + 0], bout[32*wv + 4*lg + 1],
                    bout[32*wv + 4*lg + 2], bout[32*wv + 4*lg + 3]};
        f32x4 o1 = {bout[32*wv + 16 + 4*lg + 0], bout[32*wv + 16 + 4*lg + 1],
                    bout[32*wv + 16 + 4*lg + 2], bout[32*wv + 16 + 4*lg + 3]};
        #pragma unroll
        for (int c = 0; c < 4; ++c) {
            short8 hf = *reinterpret_cast<const short8*>(lds + rd[c]);
            o0 = MFMA16(wo[0][c], hf, o0);
            o1 = MFMA16(wo[1][c], hf, o1);
        }
        float* op = out + (size_t)(b0 + lm) * HID + 32*wv + 4*lg;
        *reinterpret_cast<f4*>(op)      = o0;
        *reinterpret_cast<f4*>(op + 16) = o1;
    }
}

extern "C" void kernel_launch(void* const* d_in, const int* in_sizes, int n_in,
                              void* d_out, int out_size, void* d_ws, size_t ws_size,
                              hipStream_t stream) {
    const float* x    = (const float*)d_in[0];
    const float* h0   = (const float*)d_in[1];
    const float* Wxh  = (const float*)d_in[2];
    const float* bxh  = (const float*)d_in[3];
    const float* Whh  = (const float*)d_in[4];
    const float* Wout = (const float*)d_in[5];
    const float* bout = (const float*)d_in[6];
    (void)in_sizes; (void)n_in; (void)out_size;

    const size_t need = (size_t)BATCH * SEQ * HID * 2;  // 134 MB bf16 xh
    if (ws_size >= need) {
        __hip_bfloat16* xh = (__hip_bfloat16*)d_ws;
        xh_gemm_kernel<<<dim3(512), dim3(256), 0, stream>>>(x, Wxh, bxh, xh);
        rnn_rec1w_kernel<<<dim3(BATCH / BD), dim3(64), 0, stream>>>(
            xh, h0, Whh, Wout, bout, (float*)d_out);
    } else {
        rnn_fused_kernel<<<dim3(BATCH / BD), dim3(256), 0, stream>>>(
            x, h0, Wxh, bxh, Whh, Wout, bout, (float*)d_out);
    }
}

// Round 5
// 1552.022 us; speedup vs baseline: 1.1905x; 1.1905x over previous
//
#include <hip/hip_runtime.h>
#include <hip/hip_bf16.h>

// UnrolledRNN on MI355X (gfx950) — two-phase; dual-tile-per-wave recurrence.
// Phase 1 (parallel, all CUs): xh[b,t,:] = x[b,t,:] @ Wxh + bxh -> bf16 in d_ws.
// Phase 2 (serial, 8 blocks x 4 waves): each block owns 32 batch rows = TWO
// independent 16-row tiles (A,B). Every wave processes its j-slice (32 j) of
// BOTH tiles each step: the two tiles' MFMA/tanh/LDS chains interleave in one
// instruction stream, filling the dep-latency and barrier-rendezvous stalls
// that bound the single-tile version (R2: ~600 cyc/step exposed stall).
// ONE barrier per step serves both tiles; Whh fragments are shared.
// sigma exchange (validated R3): acc slot (u, row=4lg+r) of wave wv holds
// j = 32wv + 8lg + 4u + r, so each wave's packed tanh output IS its own
// next-step MFMA B-fragment; one lane-linear ds_write_b128 publishes it
// conflict-free, 3 lane-linear ds_read_b128 per tile fetch the foreign frags.

#define SEQ   2048
#define HID   128
#define BATCH 256
#define BD    16

typedef __attribute__((ext_vector_type(8))) short    short8;
typedef __attribute__((ext_vector_type(4))) float    f32x4;
typedef __attribute__((ext_vector_type(4))) float    f4;
typedef __attribute__((ext_vector_type(2))) unsigned u32x2;
typedef __attribute__((ext_vector_type(4))) unsigned u32x4;

union F8 { unsigned u[4]; short8 s; };

__device__ __forceinline__ unsigned pkbf(float a, float b) {
    union { __hip_bfloat16 h[2]; unsigned u; } t;
    t.h[0] = __float2bfloat16(a);
    t.h[1] = __float2bfloat16(b);
    return t.u;
}

__device__ __forceinline__ float blo(unsigned u) {
    union { unsigned v; float f; } t; t.v = u << 16; return t.f;
}
__device__ __forceinline__ float bhi(unsigned u) {
    union { unsigned v; float f; } t; t.v = u & 0xffff0000u; return t.f;
}

__device__ __forceinline__ float tanh_fast(float x) {
    float e = __builtin_amdgcn_exp2f(x * 2.8853900817779268f);
    return 1.0f - 2.0f * __builtin_amdgcn_rcpf(e + 1.0f);
}

__device__ __forceinline__ void block_sync() {
    asm volatile("s_waitcnt lgkmcnt(0)" ::: "memory");
    __builtin_amdgcn_s_barrier();
    asm volatile("" ::: "memory");
}

#define MFMA16(A,B,C) __builtin_amdgcn_mfma_f32_16x16x32_bf16((A),(B),(C),0,0,0)

// =====================================================================
// Phase 1: xh = x @ Wxh + bxh, bf16 [BATCH*SEQ][HID] in ws (plain j order).
// =====================================================================
__launch_bounds__(256, 1)
__global__ void xh_gemm_kernel(const float* __restrict__ x,
                               const float* __restrict__ Wxh,
                               const float* __restrict__ bxh,
                               __hip_bfloat16* __restrict__ xh)
{
    const int tid  = threadIdx.x;
    const int wv   = tid >> 6;
    const int lane = tid & 63;
    const int lg   = lane >> 4;
    const int lm   = lane & 15;

    const int gw = blockIdx.x * 4 + wv;
    const int NW = gridDim.x * 4;
    const int NT = (BATCH * SEQ) / 16;

    short8 wa[8][4];
    {
        #pragma unroll
        for (int T = 0; T < 8; ++T) {
            #pragma unroll
            for (int c = 0; c < 4; ++c) {
                F8 f;
                #pragma unroll
                for (int e2 = 0; e2 < 4; ++e2) {
                    int k = 32*c + 8*lg + 2*e2;
                    f.u[e2] = pkbf(Wxh[(size_t)k*HID + 16*T + lm],
                                   Wxh[(size_t)(k+1)*HID + 16*T + lm]);
                }
                wa[T][c] = f.s;
            }
        }
    }
    float bb[8][4];
    #pragma unroll
    for (int T = 0; T < 8; ++T)
        #pragma unroll
        for (int r = 0; r < 4; ++r)
            bb[T][r] = bxh[16*T + 4*lg + r];

    for (int tile = gw; tile < NT; tile += NW) {
        const float* xp = x + (size_t)tile*16*HID + (size_t)lm*HID + 8*lg;
        f4 s[8];
        #pragma unroll
        for (int c = 0; c < 4; ++c) {
            s[2*c]   = *(const f4*)(xp + 32*c);
            s[2*c+1] = *(const f4*)(xp + 32*c + 4);
        }
        F8 xf[4];
        #pragma unroll
        for (int c = 0; c < 4; ++c) {
            xf[c].u[0] = pkbf(s[2*c][0],   s[2*c][1]);
            xf[c].u[1] = pkbf(s[2*c][2],   s[2*c][3]);
            xf[c].u[2] = pkbf(s[2*c+1][0], s[2*c+1][1]);
            xf[c].u[3] = pkbf(s[2*c+1][2], s[2*c+1][3]);
        }
        __hip_bfloat16* op = xh + (size_t)(tile*16 + lm) * HID;
        #pragma unroll
        for (int T = 0; T < 8; ++T) {
            f32x4 acc = {bb[T][0], bb[T][1], bb[T][2], bb[T][3]};
            #pragma unroll
            for (int c = 0; c < 4; ++c)
                acc = MFMA16(wa[T][c], xf[c].s, acc);
            u32x2 w;
            w[0] = pkbf(acc[0], acc[1]);
            w[1] = pkbf(acc[2], acc[3]);
            *reinterpret_cast<u32x2*>(op + 16*T + 4*lg) = w;
        }
    }
}

// =====================================================================
// Phase 2: dual-tile sigma recurrence.
// =====================================================================

// SA/SB: u32x4 slots holding xh_t for tile A/B. P = t&1. POFF = reload step.
#define REC2T_STEP(SA, SB, P, POFF, TRT)                                      \
    {                                                                          \
        f32x4 aA0, aA1, aB0, aB1;                                              \
        aA0[0] = blo(SA[0]); aA0[1] = bhi(SA[0]);                              \
        aA0[2] = blo(SA[1]); aA0[3] = bhi(SA[1]);                              \
        aA1[0] = blo(SA[2]); aA1[1] = bhi(SA[2]);                              \
        aA1[2] = blo(SA[3]); aA1[3] = bhi(SA[3]);                              \
        aB0[0] = blo(SB[0]); aB0[1] = bhi(SB[0]);                              \
        aB0[2] = blo(SB[1]); aB0[3] = bhi(SB[1]);                              \
        aB1[0] = blo(SB[2]); aB1[1] = bhi(SB[2]);                              \
        aB1[2] = blo(SB[3]); aB1[3] = bhi(SB[3]);                              \
        if ((TRT) + 4 < SEQ) {                                                 \
            SA = *(const u32x4*)(xqA + (POFF)*256);                            \
            SB = *(const u32x4*)(xqB + (POFF)*256);                            \
        }                                                                      \
        block_sync(); /* h_t frags visible in buf[P] of both tiles */          \
        {                                                                      \
            const char* rbA = ldsA + (P)*4096;                                 \
            const char* rbB = ldsB + (P)*4096;                                 \
            short8 fA0 = *(const short8*)(rbA + rd0);                          \
            short8 fB0 = *(const short8*)(rbB + rd0);                          \
            short8 fA1 = *(const short8*)(rbA + rd1);                          \
            short8 fB1 = *(const short8*)(rbB + rd1);                          \
            short8 fA2 = *(const short8*)(rbA + rd2);                          \
            short8 fB2 = *(const short8*)(rbB + rd2);                          \
            /* self-frag MFMAs first: no LDS dependency, hide read latency */  \
            aA0 = MFMA16(whhf[0][3], selfA, aA0);                              \
            aA1 = MFMA16(whhf[1][3], selfA, aA1);                              \
            aB0 = MFMA16(whhf[0][3], selfB, aB0);                              \
            aB1 = MFMA16(whhf[1][3], selfB, aB1);                              \
            aA0 = MFMA16(whhf[0][0], fA0, aA0);                                \
            aA1 = MFMA16(whhf[1][0], fA0, aA1);                                \
            aB0 = MFMA16(whhf[0][0], fB0, aB0);                                \
            aB1 = MFMA16(whhf[1][0], fB0, aB1);                                \
            aA0 = MFMA16(whhf[0][1], fA1, aA0);                                \
            aA1 = MFMA16(whhf[1][1], fA1, aA1);                                \
            aB0 = MFMA16(whhf[0][1], fB1, aB0);                                \
            aB1 = MFMA16(whhf[1][1], fB1, aB1);                                \
            aA0 = MFMA16(whhf[0][2], fA2, aA0);                                \
            aA1 = MFMA16(whhf[1][2], fA2, aA1);                                \
            aB0 = MFMA16(whhf[0][2], fB2, aB0);                                \
            aB1 = MFMA16(whhf[1][2], fB2, aB1);                                \
        }                                                                      \
        F8 nA, nB;                                                             \
        nA.u[0] = pkbf(tanh_fast(aA0[0]), tanh_fast(aA0[1]));                  \
        nA.u[1] = pkbf(tanh_fast(aA0[2]), tanh_fast(aA0[3]));                  \
        nA.u[2] = pkbf(tanh_fast(aA1[0]), tanh_fast(aA1[1]));                  \
        nA.u[3] = pkbf(tanh_fast(aA1[2]), tanh_fast(aA1[3]));                  \
        nB.u[0] = pkbf(tanh_fast(aB0[0]), tanh_fast(aB0[1]));                  \
        nB.u[1] = pkbf(tanh_fast(aB0[2]), tanh_fast(aB0[3]));                  \
        nB.u[2] = pkbf(tanh_fast(aB1[0]), tanh_fast(aB1[1]));                  \
        nB.u[3] = pkbf(tanh_fast(aB1[2]), tanh_fast(aB1[3]));                  \
        selfA = nA.s;                                                          \
        selfB = nB.s;                                                          \
        *reinterpret_cast<short8*>(ldsA + ((P)^1)*4096 + wrO) = selfA;         \
        *reinterpret_cast<short8*>(ldsB + ((P)^1)*4096 + wrO) = selfB;         \
    }

__launch_bounds__(256, 1)
__global__ void rnn_rec2t_kernel(const __hip_bfloat16* __restrict__ xh,
                                 const float* __restrict__ h0,
                                 const float* __restrict__ Whh,
                                 const float* __restrict__ Wout,
                                 const float* __restrict__ bout,
                                 float* __restrict__ out)
{
    __shared__ __align__(16) char lds[4 * 4096];  // [tile A|B][P=2][4 frags][64 lanes][16B]
    char* ldsA = lds;
    char* ldsB = lds + 2 * 4096;

    const int tid  = threadIdx.x;
    const int wv   = tid >> 6;
    const int lane = tid & 63;
    const int lg   = lane >> 4;
    const int lm   = lane & 15;
    const int b0   = blockIdx.x * 32;          // 32 batch rows per block

    const int cA = (wv + 1) & 3, cB = (wv + 2) & 3, cC = (wv + 3) & 3;
    // whhf[u][idx]: idx 0,1,2 = frags cA,cB,cC; idx 3 = self (c=wv).
    // A-frag for acc u: lane (lg,lm) elem e = Whh[32c+8lg+e][sigma(u,lm)],
    // sigma(u,row) = 32wv + 8*(row>>2) + 4u + (row&3). Shared by both tiles.
    short8 whhf[2][4];
    {
        const int scol = 32*wv + 8*(lm >> 2) + (lm & 3);
        const int cs[4] = {cA, cB, cC, wv};
        #pragma unroll
        for (int u = 0; u < 2; ++u) {
            #pragma unroll
            for (int ci = 0; ci < 4; ++ci) {
                const int c = cs[ci];
                F8 f;
                #pragma unroll
                for (int e2 = 0; e2 < 4; ++e2) {
                    int k = 32*c + 8*lg + 2*e2;
                    f.u[e2] = pkbf(Whh[(size_t)k*HID + scol + 4*u],
                                   Whh[(size_t)(k+1)*HID + scol + 4*u]);
                }
                whhf[u][ci] = f.s;
            }
        }
    }

    // lane-linear LDS offsets (conflict-free)
    const int rd0 = cA*1024 + lane*16;
    const int rd1 = cB*1024 + lane*16;
    const int rd2 = cC*1024 + lane*16;
    const int wrO = wv*1024 + lane*16;

    // init self-frags + buf[0] from h0 (frag elem e = h0[row][32wv+8lg+e])
    short8 selfA, selfB;
    {
        const float* hpA = h0 + (size_t)(b0 + lm) * HID + 32*wv + 8*lg;
        const float* hpB = hpA + (size_t)16 * HID;
        f4 a0 = *(const f4*)(hpA), a1 = *(const f4*)(hpA + 4);
        f4 b0v = *(const f4*)(hpB), b1 = *(const f4*)(hpB + 4);
        F8 fa, fb;
        fa.u[0] = pkbf(a0[0], a0[1]);  fa.u[1] = pkbf(a0[2], a0[3]);
        fa.u[2] = pkbf(a1[0], a1[1]);  fa.u[3] = pkbf(a1[2], a1[3]);
        fb.u[0] = pkbf(b0v[0], b0v[1]); fb.u[1] = pkbf(b0v[2], b0v[3]);
        fb.u[2] = pkbf(b1[0], b1[1]);  fb.u[3] = pkbf(b1[2], b1[3]);
        selfA = fa.s; selfB = fb.s;
        *reinterpret_cast<short8*>(ldsA + wrO) = selfA;
        *reinterpret_cast<short8*>(ldsB + wrO) = selfB;
    }

    // xh streams: lane loads 16B/step/tile at xh[row][t][32wv+8lg]
    const char* xqA = (const char*)xh + (size_t)(b0 + lm) * SEQ * 256
                    + 64*wv + 16*lg;
    const char* xqB = xqA + (size_t)16 * SEQ * 256;

    u32x4 sA0 = *(const u32x4*)(xqA + 0*256);
    u32x4 sA1 = *(const u32x4*)(xqA + 1*256);
    u32x4 sA2 = *(const u32x4*)(xqA + 2*256);
    u32x4 sA3 = *(const u32x4*)(xqA + 3*256);
    u32x4 sB0 = *(const u32x4*)(xqB + 0*256);
    u32x4 sB1 = *(const u32x4*)(xqB + 1*256);
    u32x4 sB2 = *(const u32x4*)(xqB + 2*256);
    u32x4 sB3 = *(const u32x4*)(xqB + 3*256);

    for (int t = 0; t < SEQ; t += 4) {
        REC2T_STEP(sA0, sB0, 0, 4, t);
        REC2T_STEP(sA1, sB1, 1, 5, t + 1);
        REC2T_STEP(sA2, sB2, 0, 6, t + 2);
        REC2T_STEP(sA3, sB3, 1, 7, t + 3);
        xqA += 4 * 256;
        xqB += 4 * 256;
    }

    // epilogue: out = h_last @ Wout + bout; h_last frags in buf[0] of each tile
    block_sync();
    {
        short8 wof[2][4];
        const int col = 32*wv + lm;
        #pragma unroll
        for (int T = 0; T < 2; ++T) {
            #pragma unroll
            for (int c = 0; c < 4; ++c) {
                F8 f;
                #pragma unroll
                for (int e2 = 0; e2 < 4; ++e2) {
                    int k = 32*c + 8*lg + 2*e2;
                    f.u[e2] = pkbf(Wout[(size_t)k*HID + col + 16*T],
                                   Wout[(size_t)(k+1)*HID + col + 16*T]);
                }
                wof[T][c] = f.s;
            }
        }
        #pragma unroll
        for (int tl = 0; tl < 2; ++tl) {
            const char* hb = (tl == 0) ? ldsA : ldsB;
            f32x4 o0 = {bout[32*wv + 4*lg + 0], bout[32*wv + 4*lg + 1],
                        bout[32*wv + 4*lg + 2], bout[32*wv + 4*lg + 3]};
            f32x4 o1 = {bout[32*wv + 16 + 4*lg + 0], bout[32*wv + 16 + 4*lg + 1],
                        bout[32*wv + 16 + 4*lg + 2], bout[32*wv + 16 + 4*lg + 3]};
            #pragma unroll
            for (int c = 0; c < 4; ++c) {
                short8 hf = *reinterpret_cast<const short8*>(hb + c*1024 + lane*16);
                o0 = MFMA16(wof[0][c], hf, o0);
                o1 = MFMA16(wof[1][c], hf, o1);
            }
            float* op = out + (size_t)(b0 + 16*tl + lm) * HID + 32*wv + 4*lg;
            *reinterpret_cast<f4*>(op)      = o0;
            *reinterpret_cast<f4*>(op + 16) = o1;
        }
    }
}

// =====================================================================
// Fallback: verified round-1 monolithic kernel (used if ws too small).
// =====================================================================
#define RNN_STEP(SLOT, P, POFF, TRT)                                          \
    {                                                                          \
        F8 xf[4];                                                              \
        _Pragma("unroll")                                                      \
        for (int c = 0; c < 4; ++c) {                                          \
            xf[c].u[0] = pkbf(SLOT[2*c][0],   SLOT[2*c][1]);                   \
            xf[c].u[1] = pkbf(SLOT[2*c][2],   SLOT[2*c][3]);                   \
            xf[c].u[2] = pkbf(SLOT[2*c+1][0], SLOT[2*c+1][1]);                 \
            xf[c].u[3] = pkbf(SLOT[2*c+1][2], SLOT[2*c+1][3]);                 \
        }                                                                      \
        if ((TRT) + 2 < SEQ) {                                                 \
            _Pragma("unroll")                                                  \
            for (int c = 0; c < 4; ++c) {                                      \
                SLOT[2*c]   = *(const f4*)(xq + (POFF)*HID + 32*c);            \
                SLOT[2*c+1] = *(const f4*)(xq + (POFF)*HID + 32*c + 4);        \
            }                                                                  \
        }                                                                      \
        f32x4 a0 = {bx[0][0], bx[0][1], bx[0][2], bx[0][3]};                   \
        f32x4 a1 = {bx[1][0], bx[1][1], bx[1][2], bx[1][3]};                   \
        _Pragma("unroll")                                                      \
        for (int c = 0; c < 4; ++c) {                                          \
            a0 = MFMA16(wxh[0][c], xf[c].s, a0);                               \
            a1 = MFMA16(wxh[1][c], xf[c].s, a1);                               \
        }                                                                      \
        block_sync();                                                          \
        _Pragma("unroll")                                                      \
        for (int c = 0; c < 4; ++c) {                                          \
            short8 hf = *reinterpret_cast<const short8*>(lds + (P)*4096 + rd[c]); \
            a0 = MFMA16(whh[0][c], hf, a0);                                    \
            a1 = MFMA16(whh[1][c], hf, a1);                                    \
        }                                                                      \
        u32x2 w0, w1;                                                          \
        w0[0] = pkbf(tanh_fast(a0[0]), tanh_fast(a0[1]));                      \
        w0[1] = pkbf(tanh_fast(a0[2]), tanh_fast(a0[3]));                      \
        w1[0] = pkbf(tanh_fast(a1[0]), tanh_fast(a1[1]));                      \
        w1[1] = pkbf(tanh_fast(a1[2]), tanh_fast(a1[3]));                      \
        *reinterpret_cast<u32x2*>(lds + ((P)^1)*4096 + hw[0]) = w0;            \
        *reinterpret_cast<u32x2*>(lds + ((P)^1)*4096 + hw[1]) = w1;            \
    }

__launch_bounds__(256, 1)
__global__ void rnn_fused_kernel(const float* __restrict__ x,
                                 const float* __restrict__ h0,
                                 const float* __restrict__ Wxh,
                                 const float* __restrict__ bxh,
                                 const float* __restrict__ Whh,
                                 const float* __restrict__ Wout,
                                 const float* __restrict__ bout,
                                 float* __restrict__ out)
{
    __shared__ __align__(16) char lds[2 * 4096];

    const int tid  = threadIdx.x;
    const int wv   = tid >> 6;
    const int lane = tid & 63;
    const int lg   = lane >> 4;
    const int lm   = lane & 15;
    const int b0   = blockIdx.x * BD;

    short8 wxh[2][4], whh[2][4];
    {
        const int col = 32*wv + lm;
        #pragma unroll
        for (int T = 0; T < 2; ++T) {
            #pragma unroll
            for (int c = 0; c < 4; ++c) {
                F8 fx, fh;
                #pragma unroll
                for (int e2 = 0; e2 < 4; ++e2) {
                    int k = 32*c + 8*lg + 2*e2;
                    fx.u[e2] = pkbf(Wxh[(size_t)k*HID + col + 16*T],
                                    Wxh[(size_t)(k+1)*HID + col + 16*T]);
                    fh.u[e2] = pkbf(Whh[(size_t)k*HID + col + 16*T],
                                    Whh[(size_t)(k+1)*HID + col + 16*T]);
                }
                wxh[T][c] = fx.s; whh[T][c] = fh.s;
            }
        }
    }
    float bx[2][4];
    #pragma unroll
    for (int T = 0; T < 2; ++T)
        #pragma unroll
        for (int r = 0; r < 4; ++r)
            bx[T][r] = bxh[32*wv + 16*T + 4*lg + r];

    int rd[4];
    #pragma unroll
    for (int c = 0; c < 4; ++c)
        rd[c] = (lm*256 + 64*c + 16*lg) ^ ((lm & 7) << 4);
    int hw[2];
    #pragma unroll
    for (int T = 0; T < 2; ++T)
        hw[T] = (lm*256 + 2*(32*wv + 16*T + 4*lg)) ^ ((lm & 7) << 4);

    {
        int b  = tid >> 4;
        int j0 = (tid & 15) * 8;
        const float* hp = h0 + (size_t)(b0 + b) * HID + j0;
        f4 v0 = *(const f4*)(hp);
        f4 v1 = *(const f4*)(hp + 4);
        F8 f;
        f.u[0] = pkbf(v0[0], v0[1]); f.u[1] = pkbf(v0[2], v0[3]);
        f.u[2] = pkbf(v1[0], v1[1]); f.u[3] = pkbf(v1[2], v1[3]);
        int off = (b*256 + 2*j0) ^ ((b & 7) << 4);
        *reinterpret_cast<short8*>(lds + off) = f.s;
    }

    const float* xq = x + (size_t)(b0 + lm) * SEQ * HID + 8*lg;
    f4 sA[8], sB[8];
    #pragma unroll
    for (int c = 0; c < 4; ++c) {
        sA[2*c]   = *(const f4*)(xq + 32*c);
        sA[2*c+1] = *(const f4*)(xq + 32*c + 4);
        sB[2*c]   = *(const f4*)(xq + HID + 32*c);
        sB[2*c+1] = *(const f4*)(xq + HID + 32*c + 4);
    }

    for (int t = 0; t < SEQ; t += 2) {
        RNN_STEP(sA, 0, 2, t);
        RNN_STEP(sB, 1, 3, t + 1);
        xq += 2 * HID;
    }

    block_sync();
    {
        short8 wo[2][4];
        const int col = 32*wv + lm;
        #pragma unroll
        for (int T = 0; T < 2; ++T) {
            #pragma unroll
            for (int c = 0; c < 4; ++c) {
                F8 f;
                #pragma unroll
                for (int e2 = 0; e2 < 4; ++e2) {
                    int k = 32*c + 8*lg + 2*e2;
                    f.u[e2] = pkbf(Wout[(size_t)k*HID + col + 16*T],
                                   Wout[(size_t)(k+1)*HID + col + 16*T]);
                }
                wo[T][c] = f.s;
            }
        }
        f32x4 o0 = {bout[32*wv + 4*lg + 0], bout[32*wv + 4*lg + 1],
                    bout[32*wv + 4*lg + 2], bout[32*wv + 4*lg + 3]};
        f32x4 o1 = {bout[32*wv + 16 + 4*lg + 0], bout[32*wv + 16 + 4*lg + 1],
                    bout[32*wv + 16 + 4*lg + 2], bout[32*wv + 16 + 4*lg + 3]};
        #pragma unroll
        for (int c = 0; c < 4; ++c) {
            short8 hf = *reinterpret_cast<const short8*>(lds + rd[c]);
            o0 = MFMA16(wo[0][c], hf, o0);
            o1 = MFMA16(wo[1][c], hf, o1);
        }
        float* op = out + (size_t)(b0 + lm) * HID + 32*wv + 4*lg;
        *reinterpret_cast<f4*>(op)      = o0;
        *reinterpret_cast<f4*>(op + 16) = o1;
    }
}

extern "C" void kernel_launch(void* const* d_in, const int* in_sizes, int n_in,
                              void* d_out, int out_size, void* d_ws, size_t ws_size,
                              hipStream_t stream) {
    const float* x    = (const float*)d_in[0];
    const float* h0   = (const float*)d_in[1];
    const float* Wxh  = (const float*)d_in[2];
    const float* bxh  = (const float*)d_in[3];
    const float* Whh  = (const float*)d_in[4];
    const float* Wout = (const float*)d_in[5];
    const float* bout = (const float*)d_in[6];
    (void)in_sizes; (void)n_in; (void)out_size;

    const size_t need = (size_t)BATCH * SEQ * HID * 2;  // 134 MB bf16 xh
    if (ws_size >= need) {
        __hip_bfloat16* xh = (__hip_bfloat16*)d_ws;
        xh_gemm_kernel<<<dim3(512), dim3(256), 0, stream>>>(x, Wxh, bxh, xh);
        rnn_rec2t_kernel<<<dim3(BATCH / 32), dim3(256), 0, stream>>>(
            xh, h0, Whh, Wout, bout, (float*)d_out);
    } else {
        rnn_fused_kernel<<<dim3(BATCH / BD), dim3(256), 0, stream>>>(
            x, h0, Wxh, bxh, Whh, Wout, bout, (float*)d_out);
    }
}

// Round 6
// 1046.473 us; speedup vs baseline: 1.7656x; 1.4831x over previous
//
#include <hip/hip_runtime.h>
#include <hip/hip_bf16.h>

// UnrolledRNN on MI355X (gfx950) — two-phase; split-K recurrence.
// Phase 1 (parallel, all CUs): xh[b,t,:] = x[b,t,:] @ Wxh + bxh -> bf16 in d_ws.
// Phase 2 (serial, 16 blocks x 4 waves): h = tanh(xh_t + h @ Whh).
//   SPLIT-K: wave wv owns k-slice [32wv,32wv+32) of Whh. Each step it computes
//   partials for ALL 8 output tiles from its register-resident B-frag (one
//   MFMA each, independent), exchanges f32 PARTIAL SUMS via LDS (6 writes,
//   barrier, 6 reads, add-tree), then tanh+pack -> next B-frag.
//   vs R2/R3: the LDS round-trip + 4-deep MFMA chain leave the serial path;
//   what remains is MFMA-pipe + barrier + read + adds + tanh (~500 cyc).
//   sigma permutation (validated R3/R4): output tile (w,u) slot (lg,r) holds
//   j = 32w + 8lg + 4u + r, so each wave's packed tanh output IS its next-step
//   MFMA B-fragment. All LDS ops lane-linear 16B (conflict-free, measured 0).

#define SEQ   2048
#define HID   128
#define BATCH 256
#define BD    16

typedef __attribute__((ext_vector_type(8))) short    short8;
typedef __attribute__((ext_vector_type(4))) float    f32x4;
typedef __attribute__((ext_vector_type(4))) float    f4;
typedef __attribute__((ext_vector_type(2))) unsigned u32x2;
typedef __attribute__((ext_vector_type(4))) unsigned u32x4;

union F8 { unsigned u[4]; short8 s; };

__device__ __forceinline__ unsigned pkbf(float a, float b) {
    union { __hip_bfloat16 h[2]; unsigned u; } t;
    t.h[0] = __float2bfloat16(a);
    t.h[1] = __float2bfloat16(b);
    return t.u;
}

__device__ __forceinline__ float blo(unsigned u) {
    union { unsigned v; float f; } t; t.v = u << 16; return t.f;
}
__device__ __forceinline__ float bhi(unsigned u) {
    union { unsigned v; float f; } t; t.v = u & 0xffff0000u; return t.f;
}

__device__ __forceinline__ float tanh_fast(float x) {
    float e = __builtin_amdgcn_exp2f(x * 2.8853900817779268f);
    return 1.0f - 2.0f * __builtin_amdgcn_rcpf(e + 1.0f);
}

__device__ __forceinline__ void block_sync() {
    asm volatile("s_waitcnt lgkmcnt(0)" ::: "memory");
    __builtin_amdgcn_s_barrier();
    asm volatile("" ::: "memory");
}

#define MFMA16(A,B,C) __builtin_amdgcn_mfma_f32_16x16x32_bf16((A),(B),(C),0,0,0)

// =====================================================================
// Phase 1: xh = x @ Wxh + bxh, bf16 [BATCH*SEQ][HID] in ws (plain j order).
// =====================================================================
__launch_bounds__(256, 1)
__global__ void xh_gemm_kernel(const float* __restrict__ x,
                               const float* __restrict__ Wxh,
                               const float* __restrict__ bxh,
                               __hip_bfloat16* __restrict__ xh)
{
    const int tid  = threadIdx.x;
    const int wv   = tid >> 6;
    const int lane = tid & 63;
    const int lg   = lane >> 4;
    const int lm   = lane & 15;

    const int gw = blockIdx.x * 4 + wv;
    const int NW = gridDim.x * 4;
    const int NT = (BATCH * SEQ) / 16;

    short8 wa[8][4];
    {
        #pragma unroll
        for (int T = 0; T < 8; ++T) {
            #pragma unroll
            for (int c = 0; c < 4; ++c) {
                F8 f;
                #pragma unroll
                for (int e2 = 0; e2 < 4; ++e2) {
                    int k = 32*c + 8*lg + 2*e2;
                    f.u[e2] = pkbf(Wxh[(size_t)k*HID + 16*T + lm],
                                   Wxh[(size_t)(k+1)*HID + 16*T + lm]);
                }
                wa[T][c] = f.s;
            }
        }
    }
    float bb[8][4];
    #pragma unroll
    for (int T = 0; T < 8; ++T)
        #pragma unroll
        for (int r = 0; r < 4; ++r)
            bb[T][r] = bxh[16*T + 4*lg + r];

    for (int tile = gw; tile < NT; tile += NW) {
        const float* xp = x + (size_t)tile*16*HID + (size_t)lm*HID + 8*lg;
        f4 s[8];
        #pragma unroll
        for (int c = 0; c < 4; ++c) {
            s[2*c]   = *(const f4*)(xp + 32*c);
            s[2*c+1] = *(const f4*)(xp + 32*c + 4);
        }
        F8 xf[4];
        #pragma unroll
        for (int c = 0; c < 4; ++c) {
            xf[c].u[0] = pkbf(s[2*c][0],   s[2*c][1]);
            xf[c].u[1] = pkbf(s[2*c][2],   s[2*c][3]);
            xf[c].u[2] = pkbf(s[2*c+1][0], s[2*c+1][1]);
            xf[c].u[3] = pkbf(s[2*c+1][2], s[2*c+1][3]);
        }
        __hip_bfloat16* op = xh + (size_t)(tile*16 + lm) * HID;
        #pragma unroll
        for (int T = 0; T < 8; ++T) {
            f32x4 acc = {bb[T][0], bb[T][1], bb[T][2], bb[T][3]};
            #pragma unroll
            for (int c = 0; c < 4; ++c)
                acc = MFMA16(wa[T][c], xf[c].s, acc);
            u32x2 w;
            w[0] = pkbf(acc[0], acc[1]);
            w[1] = pkbf(acc[2], acc[3]);
            *reinterpret_cast<u32x2*>(op + 16*T + 4*lg) = w;
        }
    }
}

// =====================================================================
// Phase 2: split-K recurrence.
// LDS partial zones: buf[P][dest_wave][u][src 0..2][lane] of f32x4;
// zone byte = P*24576 + dest*6144 + u*3072 + src*1024 + lane*16.
// =====================================================================

#define RECSK_STEP(S, P, POFF, TRT)                                           \
    {                                                                          \
        f32x4 own0, own1;                                                      \
        own0[0] = blo(S[0]); own0[1] = bhi(S[0]);                              \
        own0[2] = blo(S[1]); own0[3] = bhi(S[1]);                              \
        own1[0] = blo(S[2]); own1[1] = bhi(S[2]);                              \
        own1[2] = blo(S[3]); own1[3] = bhi(S[3]);                              \
        if ((TRT) + 4 < SEQ) S = *(const u32x4*)(xq + (POFF)*256);             \
        const f32x4 z = {0.f, 0.f, 0.f, 0.f};                                  \
        f32x4 g0 = z, g1 = z, g2 = z, g3 = z, g4 = z, g5 = z;                  \
        /* foreign-tile partials first: they gate the writes/barrier */        \
        g0 = MFMA16(whfF[0], self, g0);                                        \
        g1 = MFMA16(whfF[1], self, g1);                                        \
        g2 = MFMA16(whfF[2], self, g2);                                        \
        g3 = MFMA16(whfF[3], self, g3);                                        \
        g4 = MFMA16(whfF[4], self, g4);                                        \
        g5 = MFMA16(whfF[5], self, g5);                                        \
        own0 = MFMA16(whfO[0], self, own0);                                    \
        own1 = MFMA16(whfO[1], self, own1);                                    \
        {                                                                      \
            char* wb = lds + (P)*24576;                                        \
            *reinterpret_cast<f32x4*>(wb + wz[0]) = g0;                        \
            *reinterpret_cast<f32x4*>(wb + wz[1]) = g1;                        \
            *reinterpret_cast<f32x4*>(wb + wz[2]) = g2;                        \
            *reinterpret_cast<f32x4*>(wb + wz[3]) = g3;                        \
            *reinterpret_cast<f32x4*>(wb + wz[4]) = g4;                        \
            *reinterpret_cast<f32x4*>(wb + wz[5]) = g5;                        \
        }                                                                      \
        block_sync();                                                          \
        {                                                                      \
            const char* rb = lds + (P)*24576;                                  \
            f32x4 p00 = *(const f32x4*)(rb + rz[0]);                           \
            f32x4 p01 = *(const f32x4*)(rb + rz[1]);                           \
            f32x4 p02 = *(const f32x4*)(rb + rz[2]);                           \
            f32x4 p10 = *(const f32x4*)(rb + rz[3]);                           \
            f32x4 p11 = *(const f32x4*)(rb + rz[4]);                           \
            f32x4 p12 = *(const f32x4*)(rb + rz[5]);                           \
            own0 += (p00 + p01) + p02;                                         \
            own1 += (p10 + p11) + p12;                                         \
        }                                                                      \
        F8 nf;                                                                 \
        nf.u[0] = pkbf(tanh_fast(own0[0]), tanh_fast(own0[1]));                \
        nf.u[1] = pkbf(tanh_fast(own0[2]), tanh_fast(own0[3]));                \
        nf.u[2] = pkbf(tanh_fast(own1[0]), tanh_fast(own1[1]));                \
        nf.u[3] = pkbf(tanh_fast(own1[2]), tanh_fast(own1[3]));                \
        self = nf.s;                                                           \
    }

__launch_bounds__(256, 1)
__global__ void rnn_recsk_kernel(const __hip_bfloat16* __restrict__ xh,
                                 const float* __restrict__ h0,
                                 const float* __restrict__ Whh,
                                 const float* __restrict__ Wout,
                                 const float* __restrict__ bout,
                                 float* __restrict__ out)
{
    __shared__ __align__(16) char lds[2 * 24576];

    const int tid  = threadIdx.x;
    const int wv   = tid >> 6;
    const int lane = tid & 63;
    const int lg   = lane >> 4;
    const int lm   = lane & 15;
    const int b0   = blockIdx.x * BD;

    // Whh A-frags, k-slice = [32wv, 32wv+32).
    // Tile (w,u): A-frag lane (lg,lm) elem e = Whh[32wv+8lg+e][sigma(w,u,lm)],
    // sigma(w,u,m) = 32w + 8*(m>>2) + 4u + (m&3).
    // whfO[u] = own tiles (w=wv); whfF[2*i+u] = dest wave (wv+1+i)&3, i=0..2.
    short8 whfO[2], whfF[6];
    {
        #pragma unroll
        for (int i = 0; i < 4; ++i) {
            const int w = (wv + i) & 3;           // i=0 -> own
            #pragma unroll
            for (int u = 0; u < 2; ++u) {
                const int scol = 32*w + 8*(lm >> 2) + 4*u + (lm & 3);
                F8 f;
                #pragma unroll
                for (int e2 = 0; e2 < 4; ++e2) {
                    int k = 32*wv + 8*lg + 2*e2;
                    f.u[e2] = pkbf(Whh[(size_t)k*HID + scol],
                                   Whh[(size_t)(k+1)*HID + scol]);
                }
                if (i == 0) whfO[u] = f.s;
                else        whfF[2*(i-1) + u] = f.s;
            }
        }
    }

    // LDS byte offsets. Writer wv -> dest w: src slot = (wv - w - 1) & 3.
    int wz[6], rz[6];
    #pragma unroll
    for (int i = 0; i < 3; ++i) {
        const int w   = (wv + 1 + i) & 3;
        const int src = (wv - w - 1) & 3;          // 0..2
        #pragma unroll
        for (int u = 0; u < 2; ++u)
            wz[2*i + u] = w*6144 + u*3072 + src*1024 + lane*16;
    }
    #pragma unroll
    for (int u = 0; u < 2; ++u)
        #pragma unroll
        for (int s = 0; s < 3; ++s)
            rz[3*u + s] = wv*6144 + u*3072 + s*1024 + lane*16;

    // self B-frag init from h0: elem e = h0[b0+lm][32wv+8lg+e]
    short8 self;
    {
        const float* hp = h0 + (size_t)(b0 + lm) * HID + 32*wv + 8*lg;
        f4 v0 = *(const f4*)(hp);
        f4 v1 = *(const f4*)(hp + 4);
        F8 f;
        f.u[0] = pkbf(v0[0], v0[1]); f.u[1] = pkbf(v0[2], v0[3]);
        f.u[2] = pkbf(v1[0], v1[1]); f.u[3] = pkbf(v1[2], v1[3]);
        self = f.s;
    }

    // xh stream: 16B/lane/step at xh[b0+lm][t][32wv+8lg], 4-deep prefetch
    const char* xq = (const char*)xh + (size_t)(b0 + lm) * SEQ * 256
                   + 64*wv + 16*lg;

    u32x4 sA = *(const u32x4*)(xq + 0*256);
    u32x4 sB = *(const u32x4*)(xq + 1*256);
    u32x4 sC = *(const u32x4*)(xq + 2*256);
    u32x4 sD = *(const u32x4*)(xq + 3*256);

    for (int t = 0; t < SEQ; t += 4) {
        RECSK_STEP(sA, 0, 4, t);
        RECSK_STEP(sB, 1, 5, t + 1);
        RECSK_STEP(sC, 0, 6, t + 2);
        RECSK_STEP(sD, 1, 7, t + 3);
        xq += 4 * 256;
    }

    // epilogue: out = h_last @ Wout + bout.
    // self frags (c = wv) published via LDS, then plain-order output GEMM.
    block_sync();  // re-purpose buffer safely
    *reinterpret_cast<short8*>(lds + wv*1024 + lane*16) = self;
    block_sync();
    {
        short8 hf[4];
        #pragma unroll
        for (int c = 0; c < 4; ++c)
            hf[c] = *reinterpret_cast<const short8*>(lds + c*1024 + lane*16);

        #pragma unroll
        for (int Tl = 0; Tl < 2; ++Tl) {
            const int col = 32*wv + 16*Tl + lm;
            f32x4 o = {bout[32*wv + 16*Tl + 4*lg + 0],
                       bout[32*wv + 16*Tl + 4*lg + 1],
                       bout[32*wv + 16*Tl + 4*lg + 2],
                       bout[32*wv + 16*Tl + 4*lg + 3]};
            #pragma unroll
            for (int c = 0; c < 4; ++c) {
                F8 f;
                #pragma unroll
                for (int e2 = 0; e2 < 4; ++e2) {
                    int k = 32*c + 8*lg + 2*e2;
                    f.u[e2] = pkbf(Wout[(size_t)k*HID + col],
                                   Wout[(size_t)(k+1)*HID + col]);
                }
                o = MFMA16(f.s, hf[c], o);
            }
            float* op = out + (size_t)(b0 + lm) * HID + 32*wv + 16*Tl + 4*lg;
            *reinterpret_cast<f4*>(op) = o;
        }
    }
}

// =====================================================================
// Fallback: verified round-1 monolithic kernel (used if ws too small).
// =====================================================================
#define RNN_STEP(SLOT, P, POFF, TRT)                                          \
    {                                                                          \
        F8 xf[4];                                                              \
        _Pragma("unroll")                                                      \
        for (int c = 0; c < 4; ++c) {                                          \
            xf[c].u[0] = pkbf(SLOT[2*c][0],   SLOT[2*c][1]);                   \
            xf[c].u[1] = pkbf(SLOT[2*c][2],   SLOT[2*c][3]);                   \
            xf[c].u[2] = pkbf(SLOT[2*c+1][0], SLOT[2*c+1][1]);                 \
            xf[c].u[3] = pkbf(SLOT[2*c+1][2], SLOT[2*c+1][3]);                 \
        }                                                                      \
        if ((TRT) + 2 < SEQ) {                                                 \
            _Pragma("unroll")                                                  \
            for (int c = 0; c < 4; ++c) {                                      \
                SLOT[2*c]   = *(const f4*)(xq + (POFF)*HID + 32*c);            \
                SLOT[2*c+1] = *(const f4*)(xq + (POFF)*HID + 32*c + 4);        \
            }                                                                  \
        }                                                                      \
        f32x4 a0 = {bx[0][0], bx[0][1], bx[0][2], bx[0][3]};                   \
        f32x4 a1 = {bx[1][0], bx[1][1], bx[1][2], bx[1][3]};                   \
        _Pragma("unroll")                                                      \
        for (int c = 0; c < 4; ++c) {                                          \
            a0 = MFMA16(wxh[0][c], xf[c].s, a0);                               \
            a1 = MFMA16(wxh[1][c], xf[c].s, a1);                               \
        }                                                                      \
        block_sync();                                                          \
        _Pragma("unroll")                                                      \
        for (int c = 0; c < 4; ++c) {                                          \
            short8 hf = *reinterpret_cast<const short8*>(lds + (P)*4096 + rd[c]); \
            a0 = MFMA16(whh[0][c], hf, a0);                                    \
            a1 = MFMA16(whh[1][c], hf, a1);                                    \
        }                                                                      \
        u32x2 w0, w1;                                                          \
        w0[0] = pkbf(tanh_fast(a0[0]), tanh_fast(a0[1]));                      \
        w0[1] = pkbf(tanh_fast(a0[2]), tanh_fast(a0[3]));                      \
        w1[0] = pkbf(tanh_fast(a1[0]), tanh_fast(a1[1]));                      \
        w1[1] = pkbf(tanh_fast(a1[2]), tanh_fast(a1[3]));                      \
        *reinterpret_cast<u32x2*>(lds + ((P)^1)*4096 + hw[0]) = w0;            \
        *reinterpret_cast<u32x2*>(lds + ((P)^1)*4096 + hw[1]) = w1;            \
    }

__launch_bounds__(256, 1)
__global__ void rnn_fused_kernel(const float* __restrict__ x,
                                 const float* __restrict__ h0,
                                 const float* __restrict__ Wxh,
                                 const float* __restrict__ bxh,
                                 const float* __restrict__ Whh,
                                 const float* __restrict__ Wout,
                                 const float* __restrict__ bout,
                                 float* __restrict__ out)
{
    __shared__ __align__(16) char lds[2 * 4096];

    const int tid  = threadIdx.x;
    const int wv   = tid >> 6;
    const int lane = tid & 63;
    const int lg   = lane >> 4;
    const int lm   = lane & 15;
    const int b0   = blockIdx.x * BD;

    short8 wxh[2][4], whh[2][4];
    {
        const int col = 32*wv + lm;
        #pragma unroll
        for (int T = 0; T < 2; ++T) {
            #pragma unroll
            for (int c = 0; c < 4; ++c) {
                F8 fx, fh;
                #pragma unroll
                for (int e2 = 0; e2 < 4; ++e2) {
                    int k = 32*c + 8*lg + 2*e2;
                    fx.u[e2] = pkbf(Wxh[(size_t)k*HID + col + 16*T],
                                    Wxh[(size_t)(k+1)*HID + col + 16*T]);
                    fh.u[e2] = pkbf(Whh[(size_t)k*HID + col + 16*T],
                                    Whh[(size_t)(k+1)*HID + col + 16*T]);
                }
                wxh[T][c] = fx.s; whh[T][c] = fh.s;
            }
        }
    }
    float bx[2][4];
    #pragma unroll
    for (int T = 0; T < 2; ++T)
        #pragma unroll
        for (int r = 0; r < 4; ++r)
            bx[T][r] = bxh[32*wv + 16*T + 4*lg + r];

    int rd[4];
    #pragma unroll
    for (int c = 0; c < 4; ++c)
        rd[c] = (lm*256 + 64*c + 16*lg) ^ ((lm & 7) << 4);
    int hw[2];
    #pragma unroll
    for (int T = 0; T < 2; ++T)
        hw[T] = (lm*256 + 2*(32*wv + 16*T + 4*lg)) ^ ((lm & 7) << 4);

    {
        int b  = tid >> 4;
        int j0 = (tid & 15) * 8;
        const float* hp = h0 + (size_t)(b0 + b) * HID + j0;
        f4 v0 = *(const f4*)(hp);
        f4 v1 = *(const f4*)(hp + 4);
        F8 f;
        f.u[0] = pkbf(v0[0], v0[1]); f.u[1] = pkbf(v0[2], v0[3]);
        f.u[2] = pkbf(v1[0], v1[1]); f.u[3] = pkbf(v1[2], v1[3]);
        int off = (b*256 + 2*j0) ^ ((b & 7) << 4);
        *reinterpret_cast<short8*>(lds + off) = f.s;
    }

    const float* xq = x + (size_t)(b0 + lm) * SEQ * HID + 8*lg;
    f4 sA[8], sB[8];
    #pragma unroll
    for (int c = 0; c < 4; ++c) {
        sA[2*c]   = *(const f4*)(xq + 32*c);
        sA[2*c+1] = *(const f4*)(xq + 32*c + 4);
        sB[2*c]   = *(const f4*)(xq + HID + 32*c);
        sB[2*c+1] = *(const f4*)(xq + HID + 32*c + 4);
    }

    for (int t = 0; t < SEQ; t += 2) {
        RNN_STEP(sA, 0, 2, t);
        RNN_STEP(sB, 1, 3, t + 1);
        xq += 2 * HID;
    }

    block_sync();
    {
        short8 wo[2][4];
        const int col = 32*wv + lm;
        #pragma unroll
        for (int T = 0; T < 2; ++T) {
            #pragma unroll
            for (int c = 0; c < 4; ++c) {
                F8 f;
                #pragma unroll
                for (int e2 = 0; e2 < 4; ++e2) {
                    int k = 32*c + 8*lg + 2*e2;
                    f.u[e2] = pkbf(Wout[(size_t)k*HID + col + 16*T],
                                   Wout[(size_t)(k+1)*HID + col + 16*T]);
                }
                wo[T][c] = f.s;
            }
        }
        f32x4 o0 = {bout[32*wv + 4*lg + 0], bout[32*wv + 4*lg + 1],
                    bout[32*wv + 4*lg + 2], bout[32*wv + 4*lg + 3]};
        f32x4 o1 = {bout[32*wv + 16 + 4*lg + 0], bout[32*wv + 16 + 4*lg + 1],
                    bout[32*wv + 16 + 4*lg + 2], bout[32*wv + 16 + 4*lg + 3]};
        #pragma unroll
        for (int c = 0; c < 4; ++c) {
            short8 hf = *reinterpret_cast<const short8*>(lds + rd[c]);
            o0 = MFMA16(wo[0][c], hf, o0);
            o1 = MFMA16(wo[1][c], hf, o1);
        }
        float* op = out + (size_t)(b0 + lm) * HID + 32*wv + 4*lg;
        *reinterpret_cast<f4*>(op)      = o0;
        *reinterpret_cast<f4*>(op + 16) = o1;
    }
}

extern "C" void kernel_launch(void* const* d_in, const int* in_sizes, int n_in,
                              void* d_out, int out_size, void* d_ws, size_t ws_size,
                              hipStream_t stream) {
    const float* x    = (const float*)d_in[0];
    const float* h0   = (const float*)d_in[1];
    const float* Wxh  = (const float*)d_in[2];
    const float* bxh  = (const float*)d_in[3];
    const float* Whh  = (const float*)d_in[4];
    const float* Wout = (const float*)d_in[5];
    const float* bout = (const float*)d_in[6];
    (void)in_sizes; (void)n_in; (void)out_size;

    const size_t need = (size_t)BATCH * SEQ * HID * 2;  // 134 MB bf16 xh
    if (ws_size >= need) {
        __hip_bfloat16* xh = (__hip_bfloat16*)d_ws;
        xh_gemm_kernel<<<dim3(512), dim3(256), 0, stream>>>(x, Wxh, bxh, xh);
        rnn_recsk_kernel<<<dim3(BATCH / BD), dim3(256), 0, stream>>>(
            xh, h0, Whh, Wout, bout, (float*)d_out);
    } else {
        rnn_fused_kernel<<<dim3(BATCH / BD), dim3(256), 0, stream>>>(
            x, h0, Wxh, bxh, Whh, Wout, bout, (float*)d_out);
    }
}